// Round 7
// baseline (201.164 us; speedup 1.0000x reference)
//
#include <hip/hip_runtime.h>
#include <hip/hip_bf16.h>
#include <math.h>

typedef __hip_bfloat16 bf16;
typedef __attribute__((ext_vector_type(8))) short short8;
typedef __attribute__((ext_vector_type(4))) float floatx4;

#define D_MODEL 1024
#define NUM_HEADS 16
#define DK 64
#define SEQ 2048
#define BATCH 2
#define MROWS (BATCH * SEQ)          // 4096
#define KDIM 1024
#define SEG_X ((size_t)MROWS * D_MODEL)      // 4194304
#define SEG_W ((size_t)D_MODEL * D_MODEL)    // 1048576
#define QKSTRIDE 2048                         // fused Q|K row stride
#define ROPE_C (-9.2103403719761836f / 64.f)  // -ln(10000)/dk
// Q prescale: dk^-0.5 * log2(e)  -> scores arrive in log2 domain, P = exp2(S)
#define QSCALE (0.125f * 1.4426950408889634f)

__device__ inline void gload16(const void* g, void* l) {
    __builtin_amdgcn_global_load_lds(
        (const __attribute__((address_space(1))) void*)g,
        (__attribute__((address_space(3))) void*)l, 16, 0, 0);
}

// ---------------------------------------------------------------------------
// Cast fp32 inputs to bf16 workspace buffers.
// ---------------------------------------------------------------------------
__global__ __launch_bounds__(256) void cast_kernel(
    const float* __restrict__ x,  const float* __restrict__ Wq,
    const float* __restrict__ Wk, const float* __restrict__ Wv,
    const float* __restrict__ Wo,
    bf16* __restrict__ xb, bf16* __restrict__ w_all, bf16* __restrict__ wob)
{
    const size_t i = ((size_t)blockIdx.x * 256 + threadIdx.x) * 4;
    const float* src; bf16* dst;
    if (i < SEG_X)                    { src = x  + i;                       dst = xb + i; }
    else if (i < SEG_X + SEG_W)       { src = Wq + (i - SEG_X);             dst = w_all + (i - SEG_X); }
    else if (i < SEG_X + 2 * SEG_W)   { src = Wk + (i - SEG_X - SEG_W);     dst = w_all + (i - SEG_X); }
    else if (i < SEG_X + 3 * SEG_W)   { src = Wv + (i - SEG_X - 2 * SEG_W); dst = w_all + (i - SEG_X); }
    else                              { src = Wo + (i - SEG_X - 3 * SEG_W); dst = wob + (i - SEG_X - 3 * SEG_W); }
    float4 v = *reinterpret_cast<const float4*>(src);
    __hip_bfloat162 lo, hi;
    lo.x = __float2bfloat16(v.x); lo.y = __float2bfloat16(v.y);
    hi.x = __float2bfloat16(v.z); hi.y = __float2bfloat16(v.w);
    __hip_bfloat162* d2 = reinterpret_cast<__hip_bfloat162*>(dst);
    d2[0] = lo; d2[1] = hi;
}

// ---------------------------------------------------------------------------
// GEMM: 128x128 tile, 4 waves (256 thr), BK=64, double-buffered LDS (64 KB),
// T3-minimum 2-phase schedule, pure HIP / __syncthreads.  (Round-5 verified:
// WRITE_SIZE clean, conflicts 0, live set <128 regs.)
// IS_PROJ: fused RoPE (Q prescaled) -> qkb, V transposed -> vtb.
// else:    plain fp32 C store (output projection).
// ---------------------------------------------------------------------------
template <bool IS_PROJ>
__global__ __launch_bounds__(256) void gemm128_kernel(
    const bf16* __restrict__ A, const bf16* __restrict__ W,
    bf16* __restrict__ qkb, bf16* __restrict__ vtb,
    float* __restrict__ C, const int* __restrict__ pos)
{
    // [dbuf][k-half][128 rows x 32 k], row stride 32 bf16 = 64 B
    __shared__ bf16 As[2][2][128 * 32];
    __shared__ bf16 Bs[2][2][128 * 32];

    const int tileM = blockIdx.x * 128;
    const int tileN = blockIdx.y * 128;
    const int tid = threadIdx.x;
    const int w = tid >> 6, lane = tid & 63;
    const int wm = (w & 1) * 64, wn = (w >> 1) * 64;   // 2x2 waves of 64x64
    const int l15 = lane & 15, lq = lane >> 4;
    const bool isV = IS_PROJ && (tileN >= 2048);

    floatx4 acc[4][4];
    #pragma unroll
    for (int a = 0; a < 4; ++a)
        #pragma unroll
        for (int b = 0; b < 4; ++b)
            acc[a][b] = (floatx4){0.f, 0.f, 0.f, 0.f};

    // one K-tile = 128 rows x 64 k per matrix = 16 KB = 4 gload16/thread each
    auto stage = [&](int buf, int kb) {
        #pragma unroll
        for (int kh = 0; kh < 2; ++kh) {
            #pragma unroll
            for (int i = 0; i < 2; ++i) {
                const int g = i * 256 + tid;     // granule 0..511 per k-half
                const int r = g >> 2;            // row 0..127
                const int c = ((g & 3) ^ ((r >> 1) & 3)) * 8;  // swizzled src
                const int dst = (i * 256 + (tid & 0xC0)) * 8;  // linear dest
                gload16(A + (size_t)(tileM + r) * KDIM + kb + kh * 32 + c,
                        &As[buf][kh][dst]);
                gload16(W + (size_t)(tileN + r) * KDIM + kb + kh * 32 + c,
                        &Bs[buf][kh][dst]);
            }
        }
    };

    stage(0, 0);
    __syncthreads();

    const int NT = KDIM / 64;  // 16 K-tiles
    for (int t = 0; t < NT; ++t) {
        const int cur = t & 1;
        if (t + 1 < NT) stage(cur ^ 1, (t + 1) * 64);

        #pragma unroll
        for (int ks = 0; ks < 2; ++ks) {
            short8 af[4], bfr[4];
            #pragma unroll
            for (int mt = 0; mt < 4; ++mt) {
                const int r = wm + mt * 16 + l15;
                af[mt] = *reinterpret_cast<const short8*>(
                    &As[cur][ks][r * 32 + (lq ^ ((r >> 1) & 3)) * 8]);
            }
            #pragma unroll
            for (int nt = 0; nt < 4; ++nt) {
                const int r = wn + nt * 16 + l15;
                bfr[nt] = *reinterpret_cast<const short8*>(
                    &Bs[cur][ks][r * 32 + (lq ^ ((r >> 1) & 3)) * 8]);
            }
            if (isV) {
                #pragma unroll
                for (int mt = 0; mt < 4; ++mt)
                    #pragma unroll
                    for (int nt = 0; nt < 4; ++nt)
                        acc[mt][nt] = __builtin_amdgcn_mfma_f32_16x16x32_bf16(
                            bfr[nt], af[mt], acc[mt][nt], 0, 0, 0);
            } else {
                #pragma unroll
                for (int mt = 0; mt < 4; ++mt)
                    #pragma unroll
                    for (int nt = 0; nt < 4; ++nt)
                        acc[mt][nt] = __builtin_amdgcn_mfma_f32_16x16x32_bf16(
                            af[mt], bfr[nt], acc[mt][nt], 0, 0, 0);
            }
        }
        __syncthreads();
    }

    // --- epilogues (C/D layout: col = l15, row = lq*4 + reg)
    if (!IS_PROJ) {
        #pragma unroll
        for (int mt = 0; mt < 4; ++mt) {
            #pragma unroll
            for (int nt = 0; nt < 4; ++nt) {
                const int col = tileN + wn + nt * 16 + l15;
                #pragma unroll
                for (int r = 0; r < 4; ++r) {
                    const int row = tileM + wm + mt * 16 + lq * 4 + r;
                    C[(size_t)row * D_MODEL + col] = acc[mt][nt][r];
                }
            }
        }
    } else if (!isV) {
        const float qscale = (tileN < 1024) ? QSCALE : 1.0f;
        const int p64 = (pos[1] == 0);
        #pragma unroll
        for (int mt = 0; mt < 4; ++mt) {
            #pragma unroll
            for (int nt = 0; nt < 4; ++nt) {
                const int colg = tileN + wn + nt * 16 + l15;
                const int ip = (colg & 63) >> 1;
                const float freq = __expf((float)(2 * ip) * ROPE_C);
                #pragma unroll
                for (int r = 0; r < 4; ++r) {
                    const int row = tileM + wm + mt * 16 + lq * 4 + r;
                    const int s = row & (SEQ - 1);
                    const int ptok = p64 ? pos[2 * s] : pos[s];
                    const float v = acc[mt][nt][r];
                    const float pv = __shfl_xor(v, 1);
                    const float ang = (float)ptok * freq;
                    const float sn = __sinf(ang), cs = __cosf(ang);
                    const float outv = ((colg & 1) ? fmaf(pv, sn, v * cs)
                                                   : (v * cs - pv * sn)) * qscale;
                    qkb[(size_t)row * QKSTRIDE + colg] = __float2bfloat16(outv);
                }
            }
        }
    } else {
        // swapped-operand V tile: reg index = N (v-col), l15 = M (seq row)
        const int bq = tileM >> 11;
        const int tnoff = tileN - 2048;
        #pragma unroll
        for (int mt = 0; mt < 4; ++mt) {
            const int s = (tileM & (SEQ - 1)) + wm + mt * 16 + l15;
            #pragma unroll
            for (int nt = 0; nt < 4; ++nt) {
                #pragma unroll
                for (int r = 0; r < 4; ++r) {
                    const int vcol = tnoff + wn + nt * 16 + lq * 4 + r;
                    const int bh = bq * 16 + (vcol >> 6);
                    const int d = vcol & 63;
                    vtb[((size_t)bh * 64 + d) * SEQ + s] =
                        __float2bfloat16(acc[mt][nt][r]);
                }
            }
        }
    }
}

// ---------------------------------------------------------------------------
// MFMA flash attention, ROUND-7 structure:
//  (a) DE-PAIRED GRID: one 64-row q-tile per block, grid dim3(32 bh-lin, 32 qt).
//      qt = 31 - blockIdx.y (longest blocks dispatch first -> no tail);
//      bh = (x&7) + 8*((x>>3)&3) keeps each bh's 32 blocks on one XCD
//      (round-6 verified: FETCH 62.5 -> 12.4 MB, K/V L2-resident).
//      1024 blocks @ 40 KB LDS = 4 blocks/CU resident (16 waves/CU) --
//      round-6's pairing self-limited TLP to 2 blocks/CU (Occupancy 17.5%).
//  (b) PACKED-b32 Ps STORES (round-6 lesson: ds_write_b16 with 2 lanes per
//      dword serializes -> residual 4.3M conflict cycles).  Pair k-adjacent
//      P values via shfl_xor(,1); even lanes own nt={0,1} dwords, odd lanes
//      nt={2,3} (kp = parity): 8 x ds_write_b32, one lane per dword.
//      Ps = [4 waves][16 q][64 k] bf16, NO pad (8 KB); physical k-chunk =
//      logical chunk ^ g(row), g(row) = (row>>2) ^ ((row&1)<<2):
//        store banks: 2 lanes/bank (free, m136); read: aligned b128 at
//        chunk (4kp+lq)^g(l15): 2 lanes/bank per quarter-wave (free).
//  (c) T5 setprio around MFMA clusters (round-6, kept).
// ---------------------------------------------------------------------------
__global__ __launch_bounds__(256) void flash_attn_kernel(
    const bf16* __restrict__ qk, const bf16* __restrict__ vtb,
    bf16* __restrict__ O)
{
    __shared__ bf16 Ks[2][2][64][32];      // [buf][panel][row][32]
    __shared__ bf16 Vt[2][2][64][32];
    __shared__ bf16 Ps[4][16][64];         // [wave][q][k], chunk-XOR swizzled

    const int x = blockIdx.x;                       // 0..31
    const int bh = (x & 7) + 8 * ((x >> 3) & 3);    // XCD-local bh
    const int qt = 31 - blockIdx.y;                 // longest first
    const int b = bh >> 4, h = bh & 15;
    const int t = threadIdx.x;
    const int w = t >> 6, lane = t & 63;
    const int l15 = lane & 15, lq = lane >> 4;

    const bf16* qbase = qk + (size_t)b * SEQ * QKSTRIDE + h * 64;
    const bf16* kbase = qbase + 1024;
    const bf16* vbase = vtb + (size_t)bh * 64 * SEQ;

    short8 aq[2];
    {
        const bf16* qr = qbase + (size_t)(qt * 64 + 16 * w + l15) * QKSTRIDE;
        aq[0] = *reinterpret_cast<const short8*>(qr + lq * 8);
        aq[1] = *reinterpret_cast<const short8*>(qr + 32 + lq * 8);
    }

    const int srow = lane >> 2;
    const int scol = (((lane & 3) ^ (srow & 3))) * 8;   // staging swizzle
    const int rsw = lq ^ (l15 & 3);                     // K/V frag read chunk

    const short8 ones8 = {0x3F80, 0x3F80, 0x3F80, 0x3F80,
                          0x3F80, 0x3F80, 0x3F80, 0x3F80};  // bf16 1.0 x8

    floatx4 acc[4], lAcc;
    #pragma unroll
    for (int nt = 0; nt < 4; ++nt) acc[nt] = (floatx4){0.f, 0.f, 0.f, 0.f};
    lAcc = (floatx4){0.f, 0.f, 0.f, 0.f};

    const int rowloc = 16 * w + lq * 4;
    const int pi = l15 & 1, hh = l15 >> 1;          // store pairing
    const int gr = (l15 >> 2) ^ ((l15 & 1) << 2);   // read-row XOR
    unsigned int* Pw = reinterpret_cast<unsigned int*>(&Ps[w][0][0]);

    // softmax (packed-b32 LDS transpose) + PV + MFMA-l
    auto softmax_pv = [&](floatx4* accS, bool diag, int cur) {
        float p[4][4];
        #pragma unroll
        for (int nt = 0; nt < 4; ++nt) {
            const int colloc = nt * 16 + l15;
            #pragma unroll
            for (int r = 0; r < 4; ++r) {
                float e = __builtin_amdgcn_exp2f(accS[nt][r]);
                if (diag && colloc > rowloc + r) e = 0.f;
                p[nt][r] = e;
            }
        }
        // packed stores: even lanes write nt=n dwords, odd lanes nt=n+2.
        // dword (row = lq*4+r, logical chunk = 2n+4*pi+(hh>>2), elem hh&3)
        // physical chunk ^= lq ^ 4*(r&1)  (= g(row))
        #pragma unroll
        for (int n = 0; n < 2; ++n) {
            #pragma unroll
            for (int r = 0; r < 4; ++r) {
                const float a0 = p[n][r], a2 = p[n + 2][r];
                const float x0 = __shfl_xor(a0, 1);
                const float x2 = __shfl_xor(a2, 1);
                const float lo = pi ? x2 : a0;
                const float hi = pi ? a2 : x0;
                __hip_bfloat162 u;
                u.x = __float2bfloat16(lo);
                u.y = __float2bfloat16(hi);
                const int chp = (2 * n + 4 * pi + (hh >> 2)) ^ lq ^ ((r & 1) << 2);
                Pw[(lq * 4 + r) * 32 + chp * 4 + (hh & 3)] =
                    *reinterpret_cast<unsigned int*>(&u);
            }
        }
        __builtin_amdgcn_s_setprio(1);
        #pragma unroll
        for (int kp = 0; kp < 2; ++kp) {
            const short8 ap = *reinterpret_cast<const short8*>(
                &Ps[w][l15][((kp * 4 + lq) ^ gr) * 8]);
            #pragma unroll
            for (int nt = 0; nt < 4; ++nt) {
                const short8 bv = *reinterpret_cast<const short8*>(
                    &Vt[cur][kp][nt * 16 + l15][rsw * 8]);
                acc[nt] = __builtin_amdgcn_mfma_f32_16x16x32_bf16(
                    ap, bv, acc[nt], 0, 0, 0);
            }
            lAcc = __builtin_amdgcn_mfma_f32_16x16x32_bf16(
                ap, ones8, lAcc, 0, 0, 0);
        }
        __builtin_amdgcn_s_setprio(0);
    };

    auto stage = [&](int kt, int buf) {
        #pragma unroll
        for (int p = 0; p < 2; ++p) {
            gload16(kbase + (size_t)(kt * 64 + 16 * w + srow) * QKSTRIDE
                        + p * 32 + scol,
                    &Ks[buf][p][16 * w][0]);
            gload16(vbase + (size_t)(16 * w + srow) * SEQ + kt * 64
                        + p * 32 + scol,
                    &Vt[buf][p][16 * w][0]);
        }
    };

    stage(0, 0);
    __syncthreads();

    for (int kt = 0; kt <= qt; ++kt) {
        const int cur = kt & 1;
        if (kt < qt) stage(kt + 1, cur ^ 1);

        short8 bk[2][4];
        #pragma unroll
        for (int p = 0; p < 2; ++p)
            #pragma unroll
            for (int nt = 0; nt < 4; ++nt)
                bk[p][nt] = *reinterpret_cast<const short8*>(
                    &Ks[cur][p][nt * 16 + l15][rsw * 8]);

        __builtin_amdgcn_s_setprio(1);
        floatx4 sA[4];
        #pragma unroll
        for (int nt = 0; nt < 4; ++nt) sA[nt] = (floatx4){0.f, 0.f, 0.f, 0.f};
        #pragma unroll
        for (int p = 0; p < 2; ++p)
            #pragma unroll
            for (int nt = 0; nt < 4; ++nt)
                sA[nt] = __builtin_amdgcn_mfma_f32_16x16x32_bf16(
                    aq[p], bk[p][nt], sA[nt], 0, 0, 0);
        __builtin_amdgcn_s_setprio(0);

        softmax_pv(sA, kt == qt, cur);
        __syncthreads();
    }

    // Epilogue: lAcc holds row sums (replicated across l15).
    #pragma unroll
    for (int r = 0; r < 4; ++r) {
        const float inv = 1.f / lAcc[r];
        const int qrow = qt * 64 + 16 * w + lq * 4 + r;
        #pragma unroll
        for (int nt = 0; nt < 4; ++nt) {
            O[((size_t)(b * SEQ + qrow)) * D_MODEL + h * DK + nt * 16 + l15] =
                __float2bfloat16(acc[nt][r] * inv);
        }
    }
}

extern "C" void kernel_launch(void* const* d_in, const int* in_sizes, int n_in,
                              void* d_out, int out_size, void* d_ws, size_t ws_size,
                              hipStream_t stream)
{
    const float* x   = (const float*)d_in[0];
    const int*   pos = (const int*)d_in[1];
    const float* Wq  = (const float*)d_in[2];
    const float* Wk  = (const float*)d_in[3];
    const float* Wv  = (const float*)d_in[4];
    const float* Wo  = (const float*)d_in[5];
    float* out = (float*)d_out;

    bf16* xb    = (bf16*)d_ws;
    bf16* w_all = xb + SEG_X;
    bf16* wob   = w_all + 3 * SEG_W;
    bf16* qkb   = wob + SEG_W;                     // 4096 x 2048 (Q|K roped)
    bf16* vtb   = qkb + (size_t)MROWS * QKSTRIDE;  // 32 bh x 64 d x 2048 s
    bf16* ob    = xb;                              // reuse: x dead after GEMM1

    cast_kernel<<<8192, 256, 0, stream>>>(x, Wq, Wk, Wv, Wo, xb, w_all, wob);
    gemm128_kernel<true><<<dim3(32, 24), 256, 0, stream>>>(
        xb, w_all, qkb, vtb, nullptr, pos);
    flash_attn_kernel<<<dim3(32, 32), 256, 0, stream>>>(qkb, vtb, ob);
    gemm128_kernel<false><<<dim3(32, 8), 256, 0, stream>>>(
        ob, wob, nullptr, nullptr, out, nullptr);
}

// Round 8
// 193.020 us; speedup vs baseline: 1.0422x; 1.0422x over previous
//
#include <hip/hip_runtime.h>
#include <hip/hip_bf16.h>
#include <math.h>

typedef __hip_bfloat16 bf16;
typedef __attribute__((ext_vector_type(8))) short short8;
typedef __attribute__((ext_vector_type(4))) float floatx4;

#define D_MODEL 1024
#define NUM_HEADS 16
#define DK 64
#define SEQ 2048
#define BATCH 2
#define MROWS (BATCH * SEQ)          // 4096
#define KDIM 1024
#define SEG_X ((size_t)MROWS * D_MODEL)      // 4194304
#define SEG_W ((size_t)D_MODEL * D_MODEL)    // 1048576
#define QKSTRIDE 2048                         // fused Q|K row stride
#define ROPE_C (-9.2103403719761836f / 64.f)  // -ln(10000)/dk
// Q prescale: dk^-0.5 * log2(e)  -> scores arrive in log2 domain, P = exp2(S)
#define QSCALE (0.125f * 1.4426950408889634f)

__device__ inline void gload16(const void* g, void* l) {
    __builtin_amdgcn_global_load_lds(
        (const __attribute__((address_space(1))) void*)g,
        (__attribute__((address_space(3))) void*)l, 16, 0, 0);
}

// ---------------------------------------------------------------------------
// Cast fp32 inputs to bf16 workspace buffers.
// ---------------------------------------------------------------------------
__global__ __launch_bounds__(256) void cast_kernel(
    const float* __restrict__ x,  const float* __restrict__ Wq,
    const float* __restrict__ Wk, const float* __restrict__ Wv,
    const float* __restrict__ Wo,
    bf16* __restrict__ xb, bf16* __restrict__ w_all, bf16* __restrict__ wob)
{
    const size_t i = ((size_t)blockIdx.x * 256 + threadIdx.x) * 4;
    const float* src; bf16* dst;
    if (i < SEG_X)                    { src = x  + i;                       dst = xb + i; }
    else if (i < SEG_X + SEG_W)       { src = Wq + (i - SEG_X);             dst = w_all + (i - SEG_X); }
    else if (i < SEG_X + 2 * SEG_W)   { src = Wk + (i - SEG_X - SEG_W);     dst = w_all + (i - SEG_X); }
    else if (i < SEG_X + 3 * SEG_W)   { src = Wv + (i - SEG_X - 2 * SEG_W); dst = w_all + (i - SEG_X); }
    else                              { src = Wo + (i - SEG_X - 3 * SEG_W); dst = wob + (i - SEG_X - 3 * SEG_W); }
    float4 v = *reinterpret_cast<const float4*>(src);
    __hip_bfloat162 lo, hi;
    lo.x = __float2bfloat16(v.x); lo.y = __float2bfloat16(v.y);
    hi.x = __float2bfloat16(v.z); hi.y = __float2bfloat16(v.w);
    __hip_bfloat162* d2 = reinterpret_cast<__hip_bfloat162*>(dst);
    d2[0] = lo; d2[1] = hi;
}

// ---------------------------------------------------------------------------
// GEMM: 128x128 tile, 4 waves (256 thr), BK=64, double-buffered LDS (64 KB),
// T3-minimum 2-phase schedule, pure HIP / __syncthreads.  (Round-5 verified:
// WRITE_SIZE clean, conflicts 0, live set <128 regs.)
// IS_PROJ: fused RoPE (Q prescaled) -> qkb, V transposed -> vtb.
// else:    plain fp32 C store (output projection).
// ---------------------------------------------------------------------------
template <bool IS_PROJ>
__global__ __launch_bounds__(256) void gemm128_kernel(
    const bf16* __restrict__ A, const bf16* __restrict__ W,
    bf16* __restrict__ qkb, bf16* __restrict__ vtb,
    float* __restrict__ C, const int* __restrict__ pos)
{
    // [dbuf][k-half][128 rows x 32 k], row stride 32 bf16 = 64 B
    __shared__ bf16 As[2][2][128 * 32];
    __shared__ bf16 Bs[2][2][128 * 32];

    const int tileM = blockIdx.x * 128;
    const int tileN = blockIdx.y * 128;
    const int tid = threadIdx.x;
    const int w = tid >> 6, lane = tid & 63;
    const int wm = (w & 1) * 64, wn = (w >> 1) * 64;   // 2x2 waves of 64x64
    const int l15 = lane & 15, lq = lane >> 4;
    const bool isV = IS_PROJ && (tileN >= 2048);

    floatx4 acc[4][4];
    #pragma unroll
    for (int a = 0; a < 4; ++a)
        #pragma unroll
        for (int b = 0; b < 4; ++b)
            acc[a][b] = (floatx4){0.f, 0.f, 0.f, 0.f};

    // one K-tile = 128 rows x 64 k per matrix = 16 KB = 4 gload16/thread each
    auto stage = [&](int buf, int kb) {
        #pragma unroll
        for (int kh = 0; kh < 2; ++kh) {
            #pragma unroll
            for (int i = 0; i < 2; ++i) {
                const int g = i * 256 + tid;     // granule 0..511 per k-half
                const int r = g >> 2;            // row 0..127
                const int c = ((g & 3) ^ ((r >> 1) & 3)) * 8;  // swizzled src
                const int dst = (i * 256 + (tid & 0xC0)) * 8;  // linear dest
                gload16(A + (size_t)(tileM + r) * KDIM + kb + kh * 32 + c,
                        &As[buf][kh][dst]);
                gload16(W + (size_t)(tileN + r) * KDIM + kb + kh * 32 + c,
                        &Bs[buf][kh][dst]);
            }
        }
    };

    stage(0, 0);
    __syncthreads();

    const int NT = KDIM / 64;  // 16 K-tiles
    for (int t = 0; t < NT; ++t) {
        const int cur = t & 1;
        if (t + 1 < NT) stage(cur ^ 1, (t + 1) * 64);

        #pragma unroll
        for (int ks = 0; ks < 2; ++ks) {
            short8 af[4], bfr[4];
            #pragma unroll
            for (int mt = 0; mt < 4; ++mt) {
                const int r = wm + mt * 16 + l15;
                af[mt] = *reinterpret_cast<const short8*>(
                    &As[cur][ks][r * 32 + (lq ^ ((r >> 1) & 3)) * 8]);
            }
            #pragma unroll
            for (int nt = 0; nt < 4; ++nt) {
                const int r = wn + nt * 16 + l15;
                bfr[nt] = *reinterpret_cast<const short8*>(
                    &Bs[cur][ks][r * 32 + (lq ^ ((r >> 1) & 3)) * 8]);
            }
            if (isV) {
                #pragma unroll
                for (int mt = 0; mt < 4; ++mt)
                    #pragma unroll
                    for (int nt = 0; nt < 4; ++nt)
                        acc[mt][nt] = __builtin_amdgcn_mfma_f32_16x16x32_bf16(
                            bfr[nt], af[mt], acc[mt][nt], 0, 0, 0);
            } else {
                #pragma unroll
                for (int mt = 0; mt < 4; ++mt)
                    #pragma unroll
                    for (int nt = 0; nt < 4; ++nt)
                        acc[mt][nt] = __builtin_amdgcn_mfma_f32_16x16x32_bf16(
                            af[mt], bfr[nt], acc[mt][nt], 0, 0, 0);
            }
        }
        __syncthreads();
    }

    // --- epilogues (C/D layout: col = l15, row = lq*4 + reg)
    if (!IS_PROJ) {
        #pragma unroll
        for (int mt = 0; mt < 4; ++mt) {
            #pragma unroll
            for (int nt = 0; nt < 4; ++nt) {
                const int col = tileN + wn + nt * 16 + l15;
                #pragma unroll
                for (int r = 0; r < 4; ++r) {
                    const int row = tileM + wm + mt * 16 + lq * 4 + r;
                    C[(size_t)row * D_MODEL + col] = acc[mt][nt][r];
                }
            }
        }
    } else if (!isV) {
        const float qscale = (tileN < 1024) ? QSCALE : 1.0f;
        const int p64 = (pos[1] == 0);
        #pragma unroll
        for (int mt = 0; mt < 4; ++mt) {
            #pragma unroll
            for (int nt = 0; nt < 4; ++nt) {
                const int colg = tileN + wn + nt * 16 + l15;
                const int ip = (colg & 63) >> 1;
                const float freq = __expf((float)(2 * ip) * ROPE_C);
                #pragma unroll
                for (int r = 0; r < 4; ++r) {
                    const int row = tileM + wm + mt * 16 + lq * 4 + r;
                    const int s = row & (SEQ - 1);
                    const int ptok = p64 ? pos[2 * s] : pos[s];
                    const float v = acc[mt][nt][r];
                    const float pv = __shfl_xor(v, 1);
                    const float ang = (float)ptok * freq;
                    const float sn = __sinf(ang), cs = __cosf(ang);
                    const float outv = ((colg & 1) ? fmaf(pv, sn, v * cs)
                                                   : (v * cs - pv * sn)) * qscale;
                    qkb[(size_t)row * QKSTRIDE + colg] = __float2bfloat16(outv);
                }
            }
        }
    } else {
        // swapped-operand V tile: reg index = N (v-col), l15 = M (seq row)
        const int bq = tileM >> 11;
        const int tnoff = tileN - 2048;
        #pragma unroll
        for (int mt = 0; mt < 4; ++mt) {
            const int s = (tileM & (SEQ - 1)) + wm + mt * 16 + l15;
            #pragma unroll
            for (int nt = 0; nt < 4; ++nt) {
                #pragma unroll
                for (int r = 0; r < 4; ++r) {
                    const int vcol = tnoff + wn + nt * 16 + lq * 4 + r;
                    const int bh = bq * 16 + (vcol >> 6);
                    const int d = vcol & 63;
                    vtb[((size_t)bh * 64 + d) * SEQ + s] =
                        __float2bfloat16(acc[mt][nt][r]);
                }
            }
        }
    }
}

// ---------------------------------------------------------------------------
// MFMA flash attention, ROUND-8 = round-6 base (paired q-tiles, 53 us proven:
// XCD remap FETCH 62->12 MB; Ps stride-40 pad; setprio) + ONE change:
//   SHARED-bv PV.  Round-7 post-mortem: the block moves ~136 KB/paired-kt
//   through the CU LDS port (~17 us of 53 at 112 B/cy) and bv (V-tile frags)
//   is read TWICE (once per tile's softmax_pv) = 64 KB of it.  Restructure:
//   exp+store BOTH tiles' P first (Ps has 8 regions now, [w]=tileB,
//   [w+4]=tileA), then one PV loop reads each bv[kp][nt] once and feeds both
//   tiles' MFMAs.  136 -> 104 KB/paired-kt (-24% LDS traffic).
//   Round-7's packed-b32/no-pad Ps is REVERTED: removing the stride-40 pad
//   re-bank-aligned rows (row*32 == 0 mod 32) making the b128 read 16-lanes/
//   4-banks -> conflicts went UP (4.3M->7.0M).  De-paired grid also reverted
//   (+35% staging redundancy; occupancy gain did not pay for it).
// ---------------------------------------------------------------------------
__global__ __launch_bounds__(256) void flash_attn_kernel(
    const bf16* __restrict__ qk, const bf16* __restrict__ vtb,
    bf16* __restrict__ O)
{
    __shared__ bf16 Ks[2][2][64][32];      // [buf][panel][row][32]
    __shared__ bf16 Vt[2][2][64][32];
    __shared__ bf16 Ps[8][2][16][40];      // [region][kp][row][40-pad]

    const int lin = blockIdx.y * 16 + blockIdx.x;          // 0..511
    const int bh  = (lin & 7) + 8 * ((lin >> 3) & 3);      // 4 bh per XCD
    const int qtA = lin >> 5;            // 0..15
    const int qtB = 31 - qtA;            // 31..16
    const int b = bh >> 4, h = bh & 15;
    const int t = threadIdx.x;
    const int w = t >> 6, lane = t & 63;
    const int l15 = lane & 15, lq = lane >> 4;

    const bf16* qbase = qk + (size_t)b * SEQ * QKSTRIDE + h * 64;
    const bf16* kbase = qbase + 1024;
    const bf16* vbase = vtb + (size_t)bh * 64 * SEQ;

    short8 aqA[2], aqB[2];
    {
        const bf16* qr = qbase + (size_t)(qtA * 64 + 16 * w + l15) * QKSTRIDE;
        aqA[0] = *reinterpret_cast<const short8*>(qr + lq * 8);
        aqA[1] = *reinterpret_cast<const short8*>(qr + 32 + lq * 8);
        qr = qbase + (size_t)(qtB * 64 + 16 * w + l15) * QKSTRIDE;
        aqB[0] = *reinterpret_cast<const short8*>(qr + lq * 8);
        aqB[1] = *reinterpret_cast<const short8*>(qr + 32 + lq * 8);
    }

    const int srow = lane >> 2;
    const int scol = (((lane & 3) ^ (srow & 3))) * 8;   // staging swizzle
    const int rsw = lq ^ (l15 & 3);                     // K/V frag read chunk
    const int psw = lq ^ (l15 >> 2);                    // Ps frag read chunk

    const short8 ones8 = {0x3F80, 0x3F80, 0x3F80, 0x3F80,
                          0x3F80, 0x3F80, 0x3F80, 0x3F80};  // bf16 1.0 x8

    floatx4 accA[4], accB[4], lAcc[2];
    #pragma unroll
    for (int nt = 0; nt < 4; ++nt) {
        accA[nt] = (floatx4){0.f, 0.f, 0.f, 0.f};
        accB[nt] = (floatx4){0.f, 0.f, 0.f, 0.f};
    }
    lAcc[0] = (floatx4){0.f, 0.f, 0.f, 0.f};
    lAcc[1] = (floatx4){0.f, 0.f, 0.f, 0.f};

    const int rowloc = 16 * w + lq * 4;

    // exp2 + swizzled Ps store into region 'reg' (stride-40 scheme, r6-proven)
    auto exp_store = [&](floatx4* accS, bool diag, int reg) {
        #pragma unroll
        for (int nt = 0; nt < 4; ++nt) {
            const int colloc = nt * 16 + l15;
            #pragma unroll
            for (int r = 0; r < 4; ++r) {
                float e = __builtin_amdgcn_exp2f(accS[nt][r]);
                if (diag && colloc > rowloc + r) e = 0.f;
                Ps[reg][nt >> 1][lq * 4 + r]
                  [((((nt & 1) * 2 + (l15 >> 3)) ^ lq) * 8) + (l15 & 7)] =
                    __float2bfloat16(e);
            }
        }
    };

    auto stage = [&](int kt, int buf) {
        #pragma unroll
        for (int p = 0; p < 2; ++p) {
            gload16(kbase + (size_t)(kt * 64 + 16 * w + srow) * QKSTRIDE
                        + p * 32 + scol,
                    &Ks[buf][p][16 * w][0]);
            gload16(vbase + (size_t)(16 * w + srow) * SEQ + kt * 64
                        + p * 32 + scol,
                    &Vt[buf][p][16 * w][0]);
        }
    };

    stage(0, 0);
    __syncthreads();

    for (int kt = 0; kt <= qtB; ++kt) {
        const int cur = kt & 1;
        if (kt < qtB) stage(kt + 1, cur ^ 1);

        short8 bk[2][4];
        #pragma unroll
        for (int p = 0; p < 2; ++p)
            #pragma unroll
            for (int nt = 0; nt < 4; ++nt)
                bk[p][nt] = *reinterpret_cast<const short8*>(
                    &Ks[cur][p][nt * 16 + l15][rsw * 8]);

        __builtin_amdgcn_s_setprio(1);
        floatx4 sB[4];
        #pragma unroll
        for (int nt = 0; nt < 4; ++nt) sB[nt] = (floatx4){0.f, 0.f, 0.f, 0.f};
        #pragma unroll
        for (int p = 0; p < 2; ++p)
            #pragma unroll
            for (int nt = 0; nt < 4; ++nt)
                sB[nt] = __builtin_amdgcn_mfma_f32_16x16x32_bf16(
                    aqB[p], bk[p][nt], sB[nt], 0, 0, 0);
        __builtin_amdgcn_s_setprio(0);

        if (kt <= qtA) {
            // --- paired path: both tiles active; shared-bv PV
            __builtin_amdgcn_s_setprio(1);
            floatx4 sA[4];
            #pragma unroll
            for (int nt = 0; nt < 4; ++nt) sA[nt] = (floatx4){0.f, 0.f, 0.f, 0.f};
            #pragma unroll
            for (int p = 0; p < 2; ++p)
                #pragma unroll
                for (int nt = 0; nt < 4; ++nt)
                    sA[nt] = __builtin_amdgcn_mfma_f32_16x16x32_bf16(
                        aqA[p], bk[p][nt], sA[nt], 0, 0, 0);
            __builtin_amdgcn_s_setprio(0);

            exp_store(sB, kt == qtB, w);
            exp_store(sA, kt == qtA, w + 4);

            #pragma unroll
            for (int kp = 0; kp < 2; ++kp) {
                const short8 apB = *reinterpret_cast<const short8*>(
                    &Ps[w][kp][l15][psw * 8]);
                const short8 apA = *reinterpret_cast<const short8*>(
                    &Ps[w + 4][kp][l15][psw * 8]);
                short8 bv[4];
                #pragma unroll
                for (int nt = 0; nt < 4; ++nt)
                    bv[nt] = *reinterpret_cast<const short8*>(
                        &Vt[cur][kp][nt * 16 + l15][rsw * 8]);
                __builtin_amdgcn_s_setprio(1);
                #pragma unroll
                for (int nt = 0; nt < 4; ++nt)
                    accB[nt] = __builtin_amdgcn_mfma_f32_16x16x32_bf16(
                        apB, bv[nt], accB[nt], 0, 0, 0);
                lAcc[1] = __builtin_amdgcn_mfma_f32_16x16x32_bf16(
                    apB, ones8, lAcc[1], 0, 0, 0);
                #pragma unroll
                for (int nt = 0; nt < 4; ++nt)
                    accA[nt] = __builtin_amdgcn_mfma_f32_16x16x32_bf16(
                        apA, bv[nt], accA[nt], 0, 0, 0);
                lAcc[0] = __builtin_amdgcn_mfma_f32_16x16x32_bf16(
                    apA, ones8, lAcc[0], 0, 0, 0);
                __builtin_amdgcn_s_setprio(0);
            }
        } else {
            // --- single-tile path (kt > qtA): tile B only
            exp_store(sB, kt == qtB, w);
            #pragma unroll
            for (int kp = 0; kp < 2; ++kp) {
                const short8 apB = *reinterpret_cast<const short8*>(
                    &Ps[w][kp][l15][psw * 8]);
                __builtin_amdgcn_s_setprio(1);
                #pragma unroll
                for (int nt = 0; nt < 4; ++nt) {
                    const short8 bv = *reinterpret_cast<const short8*>(
                        &Vt[cur][kp][nt * 16 + l15][rsw * 8]);
                    accB[nt] = __builtin_amdgcn_mfma_f32_16x16x32_bf16(
                        apB, bv, accB[nt], 0, 0, 0);
                }
                lAcc[1] = __builtin_amdgcn_mfma_f32_16x16x32_bf16(
                    apB, ones8, lAcc[1], 0, 0, 0);
                __builtin_amdgcn_s_setprio(0);
            }
        }
        __syncthreads();
    }

    // Epilogue: lAcc holds the row sums (replicated across l15).
    auto epilogue = [&](floatx4* accO, floatx4& accL, int qt) {
        #pragma unroll
        for (int r = 0; r < 4; ++r) {
            const float inv = 1.f / accL[r];
            const int qrow = qt * 64 + 16 * w + lq * 4 + r;
            #pragma unroll
            for (int nt = 0; nt < 4; ++nt) {
                O[((size_t)(b * SEQ + qrow)) * D_MODEL + h * DK + nt * 16 + l15] =
                    __float2bfloat16(accO[nt][r] * inv);
            }
        }
    };
    epilogue(accA, lAcc[0], qtA);
    epilogue(accB, lAcc[1], qtB);
}

extern "C" void kernel_launch(void* const* d_in, const int* in_sizes, int n_in,
                              void* d_out, int out_size, void* d_ws, size_t ws_size,
                              hipStream_t stream)
{
    const float* x   = (const float*)d_in[0];
    const int*   pos = (const int*)d_in[1];
    const float* Wq  = (const float*)d_in[2];
    const float* Wk  = (const float*)d_in[3];
    const float* Wv  = (const float*)d_in[4];
    const float* Wo  = (const float*)d_in[5];
    float* out = (float*)d_out;

    bf16* xb    = (bf16*)d_ws;
    bf16* w_all = xb + SEG_X;
    bf16* wob   = w_all + 3 * SEG_W;
    bf16* qkb   = wob + SEG_W;                     // 4096 x 2048 (Q|K roped)
    bf16* vtb   = qkb + (size_t)MROWS * QKSTRIDE;  // 32 bh x 64 d x 2048 s
    bf16* ob    = xb;                              // reuse: x dead after GEMM1

    cast_kernel<<<8192, 256, 0, stream>>>(x, Wq, Wk, Wv, Wo, xb, w_all, wob);
    gemm128_kernel<true><<<dim3(32, 24), 256, 0, stream>>>(
        xb, w_all, qkb, vtb, nullptr, pos);
    flash_attn_kernel<<<dim3(16, 32), 256, 0, stream>>>(qkb, vtb, ob);
    gemm128_kernel<false><<<dim3(32, 8), 256, 0, stream>>>(
        ob, wob, nullptr, nullptr, out, nullptr);
}

// Round 9
// 191.525 us; speedup vs baseline: 1.0503x; 1.0078x over previous
//
#include <hip/hip_runtime.h>
#include <hip/hip_bf16.h>
#include <math.h>

typedef __hip_bfloat16 bf16;
typedef __attribute__((ext_vector_type(8))) short short8;
typedef __attribute__((ext_vector_type(4))) float floatx4;

#define D_MODEL 1024
#define NUM_HEADS 16
#define DK 64
#define SEQ 2048
#define BATCH 2
#define MROWS (BATCH * SEQ)          // 4096
#define KDIM 1024
#define SEG_X ((size_t)MROWS * D_MODEL)      // 4194304
#define SEG_W ((size_t)D_MODEL * D_MODEL)    // 1048576
#define QKSTRIDE 2048                         // fused Q|K row stride
#define ROPE_C (-9.2103403719761836f / 64.f)  // -ln(10000)/dk
// Q prescale: dk^-0.5 * log2(e)  -> scores arrive in log2 domain, P = exp2(S)
#define QSCALE (0.125f * 1.4426950408889634f)

__device__ inline void gload16(const void* g, void* l) {
    __builtin_amdgcn_global_load_lds(
        (const __attribute__((address_space(1))) void*)g,
        (__attribute__((address_space(3))) void*)l, 16, 0, 0);
}

// ---------------------------------------------------------------------------
// Cast fp32 inputs to bf16 workspace buffers.
// ---------------------------------------------------------------------------
__global__ __launch_bounds__(256) void cast_kernel(
    const float* __restrict__ x,  const float* __restrict__ Wq,
    const float* __restrict__ Wk, const float* __restrict__ Wv,
    const float* __restrict__ Wo,
    bf16* __restrict__ xb, bf16* __restrict__ w_all, bf16* __restrict__ wob)
{
    const size_t i = ((size_t)blockIdx.x * 256 + threadIdx.x) * 4;
    const float* src; bf16* dst;
    if (i < SEG_X)                    { src = x  + i;                       dst = xb + i; }
    else if (i < SEG_X + SEG_W)       { src = Wq + (i - SEG_X);             dst = w_all + (i - SEG_X); }
    else if (i < SEG_X + 2 * SEG_W)   { src = Wk + (i - SEG_X - SEG_W);     dst = w_all + (i - SEG_X); }
    else if (i < SEG_X + 3 * SEG_W)   { src = Wv + (i - SEG_X - 2 * SEG_W); dst = w_all + (i - SEG_X); }
    else                              { src = Wo + (i - SEG_X - 3 * SEG_W); dst = wob + (i - SEG_X - 3 * SEG_W); }
    float4 v = *reinterpret_cast<const float4*>(src);
    __hip_bfloat162 lo, hi;
    lo.x = __float2bfloat16(v.x); lo.y = __float2bfloat16(v.y);
    hi.x = __float2bfloat16(v.z); hi.y = __float2bfloat16(v.w);
    __hip_bfloat162* d2 = reinterpret_cast<__hip_bfloat162*>(dst);
    d2[0] = lo; d2[1] = hi;
}

// ---------------------------------------------------------------------------
// GEMM: 128x128 tile, 4 waves (256 thr), BK=64, double-buffered LDS (64 KB),
// T3-minimum 2-phase schedule, pure HIP / __syncthreads.  (Round-5 verified:
// WRITE_SIZE clean, conflicts 0, live set <128 regs.)
// IS_PROJ: fused RoPE (Q prescaled) -> qkb, V transposed -> vtb.
// else:    plain fp32 C store (output projection).
// ---------------------------------------------------------------------------
template <bool IS_PROJ>
__global__ __launch_bounds__(256) void gemm128_kernel(
    const bf16* __restrict__ A, const bf16* __restrict__ W,
    bf16* __restrict__ qkb, bf16* __restrict__ vtb,
    float* __restrict__ C, const int* __restrict__ pos)
{
    // [dbuf][k-half][128 rows x 32 k], row stride 32 bf16 = 64 B
    __shared__ bf16 As[2][2][128 * 32];
    __shared__ bf16 Bs[2][2][128 * 32];

    const int tileM = blockIdx.x * 128;
    const int tileN = blockIdx.y * 128;
    const int tid = threadIdx.x;
    const int w = tid >> 6, lane = tid & 63;
    const int wm = (w & 1) * 64, wn = (w >> 1) * 64;   // 2x2 waves of 64x64
    const int l15 = lane & 15, lq = lane >> 4;
    const bool isV = IS_PROJ && (tileN >= 2048);

    floatx4 acc[4][4];
    #pragma unroll
    for (int a = 0; a < 4; ++a)
        #pragma unroll
        for (int b = 0; b < 4; ++b)
            acc[a][b] = (floatx4){0.f, 0.f, 0.f, 0.f};

    // one K-tile = 128 rows x 64 k per matrix = 16 KB = 4 gload16/thread each
    auto stage = [&](int buf, int kb) {
        #pragma unroll
        for (int kh = 0; kh < 2; ++kh) {
            #pragma unroll
            for (int i = 0; i < 2; ++i) {
                const int g = i * 256 + tid;     // granule 0..511 per k-half
                const int r = g >> 2;            // row 0..127
                const int c = ((g & 3) ^ ((r >> 1) & 3)) * 8;  // swizzled src
                const int dst = (i * 256 + (tid & 0xC0)) * 8;  // linear dest
                gload16(A + (size_t)(tileM + r) * KDIM + kb + kh * 32 + c,
                        &As[buf][kh][dst]);
                gload16(W + (size_t)(tileN + r) * KDIM + kb + kh * 32 + c,
                        &Bs[buf][kh][dst]);
            }
        }
    };

    stage(0, 0);
    __syncthreads();

    const int NT = KDIM / 64;  // 16 K-tiles
    for (int t = 0; t < NT; ++t) {
        const int cur = t & 1;
        if (t + 1 < NT) stage(cur ^ 1, (t + 1) * 64);

        #pragma unroll
        for (int ks = 0; ks < 2; ++ks) {
            short8 af[4], bfr[4];
            #pragma unroll
            for (int mt = 0; mt < 4; ++mt) {
                const int r = wm + mt * 16 + l15;
                af[mt] = *reinterpret_cast<const short8*>(
                    &As[cur][ks][r * 32 + (lq ^ ((r >> 1) & 3)) * 8]);
            }
            #pragma unroll
            for (int nt = 0; nt < 4; ++nt) {
                const int r = wn + nt * 16 + l15;
                bfr[nt] = *reinterpret_cast<const short8*>(
                    &Bs[cur][ks][r * 32 + (lq ^ ((r >> 1) & 3)) * 8]);
            }
            if (isV) {
                #pragma unroll
                for (int mt = 0; mt < 4; ++mt)
                    #pragma unroll
                    for (int nt = 0; nt < 4; ++nt)
                        acc[mt][nt] = __builtin_amdgcn_mfma_f32_16x16x32_bf16(
                            bfr[nt], af[mt], acc[mt][nt], 0, 0, 0);
            } else {
                #pragma unroll
                for (int mt = 0; mt < 4; ++mt)
                    #pragma unroll
                    for (int nt = 0; nt < 4; ++nt)
                        acc[mt][nt] = __builtin_amdgcn_mfma_f32_16x16x32_bf16(
                            af[mt], bfr[nt], acc[mt][nt], 0, 0, 0);
            }
        }
        __syncthreads();
    }

    // --- epilogues (C/D layout: col = l15, row = lq*4 + reg)
    if (!IS_PROJ) {
        #pragma unroll
        for (int mt = 0; mt < 4; ++mt) {
            #pragma unroll
            for (int nt = 0; nt < 4; ++nt) {
                const int col = tileN + wn + nt * 16 + l15;
                #pragma unroll
                for (int r = 0; r < 4; ++r) {
                    const int row = tileM + wm + mt * 16 + lq * 4 + r;
                    C[(size_t)row * D_MODEL + col] = acc[mt][nt][r];
                }
            }
        }
    } else if (!isV) {
        const float qscale = (tileN < 1024) ? QSCALE : 1.0f;
        const int p64 = (pos[1] == 0);
        #pragma unroll
        for (int mt = 0; mt < 4; ++mt) {
            #pragma unroll
            for (int nt = 0; nt < 4; ++nt) {
                const int colg = tileN + wn + nt * 16 + l15;
                const int ip = (colg & 63) >> 1;
                const float freq = __expf((float)(2 * ip) * ROPE_C);
                #pragma unroll
                for (int r = 0; r < 4; ++r) {
                    const int row = tileM + wm + mt * 16 + lq * 4 + r;
                    const int s = row & (SEQ - 1);
                    const int ptok = p64 ? pos[2 * s] : pos[s];
                    const float v = acc[mt][nt][r];
                    const float pv = __shfl_xor(v, 1);
                    const float ang = (float)ptok * freq;
                    const float sn = __sinf(ang), cs = __cosf(ang);
                    const float outv = ((colg & 1) ? fmaf(pv, sn, v * cs)
                                                   : (v * cs - pv * sn)) * qscale;
                    qkb[(size_t)row * QKSTRIDE + colg] = __float2bfloat16(outv);
                }
            }
        }
    } else {
        // swapped-operand V tile: reg index = N (v-col), l15 = M (seq row)
        const int bq = tileM >> 11;
        const int tnoff = tileN - 2048;
        #pragma unroll
        for (int mt = 0; mt < 4; ++mt) {
            const int s = (tileM & (SEQ - 1)) + wm + mt * 16 + l15;
            #pragma unroll
            for (int nt = 0; nt < 4; ++nt) {
                #pragma unroll
                for (int r = 0; r < 4; ++r) {
                    const int vcol = tnoff + wn + nt * 16 + lq * 4 + r;
                    const int bh = bq * 16 + (vcol >> 6);
                    const int d = vcol & 63;
                    vtb[((size_t)bh * 64 + d) * SEQ + s] =
                        __float2bfloat16(acc[mt][nt][r]);
                }
            }
        }
    }
}

// ---------------------------------------------------------------------------
// MFMA flash attention, ROUND-9 = round-8 base (paired q-tiles, shared-bv PV,
// stride-40 Ps, XCD remap, setprio) + ONE change:
//   K/V LDS SWIZZLE FIXED to the gemm-proven bits.  Old: scol used (r&3),
//   rsw = lq ^ (l15&3) -> lanes l15 in {0,4,8,12} hit the same row-parity
//   window AND the same chunk -> same 4 banks -> 4-way conflict on every
//   bk/bv ds_read_b128 (~430 cy/paired-iter ~= the 3.75M counter).  The gemm
//   kernels use c = lq ^ ((r>>1)&3) on the identical 64B-row layout and
//   measure 0 conflicts (aliasing lanes land 2-way = free, m136).
//   New pair (both-sides-or-neither, rule #21):
//     staging src:  scol = ((lane&3) ^ ((lane>>3)&3)) * 8
//     frag read:    rsw  = lq ^ ((l15>>1)&3)
//   (physical chunk c of row r holds logical c^((r>>1)&3); nt*16 == 0 mod 8
//    so row bits reduce to l15 bits on read.)
// ---------------------------------------------------------------------------
__global__ __launch_bounds__(256) void flash_attn_kernel(
    const bf16* __restrict__ qk, const bf16* __restrict__ vtb,
    bf16* __restrict__ O)
{
    __shared__ bf16 Ks[2][2][64][32];      // [buf][panel][row][32]
    __shared__ bf16 Vt[2][2][64][32];
    __shared__ bf16 Ps[8][2][16][40];      // [region][kp][row][40-pad]

    const int lin = blockIdx.y * 16 + blockIdx.x;          // 0..511
    const int bh  = (lin & 7) + 8 * ((lin >> 3) & 3);      // 4 bh per XCD
    const int qtA = lin >> 5;            // 0..15
    const int qtB = 31 - qtA;            // 31..16
    const int b = bh >> 4, h = bh & 15;
    const int t = threadIdx.x;
    const int w = t >> 6, lane = t & 63;
    const int l15 = lane & 15, lq = lane >> 4;

    const bf16* qbase = qk + (size_t)b * SEQ * QKSTRIDE + h * 64;
    const bf16* kbase = qbase + 1024;
    const bf16* vbase = vtb + (size_t)bh * 64 * SEQ;

    short8 aqA[2], aqB[2];
    {
        const bf16* qr = qbase + (size_t)(qtA * 64 + 16 * w + l15) * QKSTRIDE;
        aqA[0] = *reinterpret_cast<const short8*>(qr + lq * 8);
        aqA[1] = *reinterpret_cast<const short8*>(qr + 32 + lq * 8);
        qr = qbase + (size_t)(qtB * 64 + 16 * w + l15) * QKSTRIDE;
        aqB[0] = *reinterpret_cast<const short8*>(qr + lq * 8);
        aqB[1] = *reinterpret_cast<const short8*>(qr + 32 + lq * 8);
    }

    const int srow = lane >> 2;
    const int scol = (((lane & 3) ^ ((lane >> 3) & 3))) * 8;  // staging swizzle
    const int rsw = lq ^ ((l15 >> 1) & 3);                    // K/V frag read
    const int psw = lq ^ (l15 >> 2);                          // Ps frag read

    const short8 ones8 = {0x3F80, 0x3F80, 0x3F80, 0x3F80,
                          0x3F80, 0x3F80, 0x3F80, 0x3F80};  // bf16 1.0 x8

    floatx4 accA[4], accB[4], lAcc[2];
    #pragma unroll
    for (int nt = 0; nt < 4; ++nt) {
        accA[nt] = (floatx4){0.f, 0.f, 0.f, 0.f};
        accB[nt] = (floatx4){0.f, 0.f, 0.f, 0.f};
    }
    lAcc[0] = (floatx4){0.f, 0.f, 0.f, 0.f};
    lAcc[1] = (floatx4){0.f, 0.f, 0.f, 0.f};

    const int rowloc = 16 * w + lq * 4;

    // exp2 + swizzled Ps store into region 'reg' (stride-40 scheme, r6-proven)
    auto exp_store = [&](floatx4* accS, bool diag, int reg) {
        #pragma unroll
        for (int nt = 0; nt < 4; ++nt) {
            const int colloc = nt * 16 + l15;
            #pragma unroll
            for (int r = 0; r < 4; ++r) {
                float e = __builtin_amdgcn_exp2f(accS[nt][r]);
                if (diag && colloc > rowloc + r) e = 0.f;
                Ps[reg][nt >> 1][lq * 4 + r]
                  [((((nt & 1) * 2 + (l15 >> 3)) ^ lq) * 8) + (l15 & 7)] =
                    __float2bfloat16(e);
            }
        }
    };

    auto stage = [&](int kt, int buf) {
        #pragma unroll
        for (int p = 0; p < 2; ++p) {
            gload16(kbase + (size_t)(kt * 64 + 16 * w + srow) * QKSTRIDE
                        + p * 32 + scol,
                    &Ks[buf][p][16 * w][0]);
            gload16(vbase + (size_t)(16 * w + srow) * SEQ + kt * 64
                        + p * 32 + scol,
                    &Vt[buf][p][16 * w][0]);
        }
    };

    stage(0, 0);
    __syncthreads();

    for (int kt = 0; kt <= qtB; ++kt) {
        const int cur = kt & 1;
        if (kt < qtB) stage(kt + 1, cur ^ 1);

        short8 bk[2][4];
        #pragma unroll
        for (int p = 0; p < 2; ++p)
            #pragma unroll
            for (int nt = 0; nt < 4; ++nt)
                bk[p][nt] = *reinterpret_cast<const short8*>(
                    &Ks[cur][p][nt * 16 + l15][rsw * 8]);

        __builtin_amdgcn_s_setprio(1);
        floatx4 sB[4];
        #pragma unroll
        for (int nt = 0; nt < 4; ++nt) sB[nt] = (floatx4){0.f, 0.f, 0.f, 0.f};
        #pragma unroll
        for (int p = 0; p < 2; ++p)
            #pragma unroll
            for (int nt = 0; nt < 4; ++nt)
                sB[nt] = __builtin_amdgcn_mfma_f32_16x16x32_bf16(
                    aqB[p], bk[p][nt], sB[nt], 0, 0, 0);
        __builtin_amdgcn_s_setprio(0);

        if (kt <= qtA) {
            // --- paired path: both tiles active; shared-bv PV
            __builtin_amdgcn_s_setprio(1);
            floatx4 sA[4];
            #pragma unroll
            for (int nt = 0; nt < 4; ++nt) sA[nt] = (floatx4){0.f, 0.f, 0.f, 0.f};
            #pragma unroll
            for (int p = 0; p < 2; ++p)
                #pragma unroll
                for (int nt = 0; nt < 4; ++nt)
                    sA[nt] = __builtin_amdgcn_mfma_f32_16x16x32_bf16(
                        aqA[p], bk[p][nt], sA[nt], 0, 0, 0);
            __builtin_amdgcn_s_setprio(0);

            exp_store(sB, kt == qtB, w);
            exp_store(sA, kt == qtA, w + 4);

            #pragma unroll
            for (int kp = 0; kp < 2; ++kp) {
                const short8 apB = *reinterpret_cast<const short8*>(
                    &Ps[w][kp][l15][psw * 8]);
                const short8 apA = *reinterpret_cast<const short8*>(
                    &Ps[w + 4][kp][l15][psw * 8]);
                short8 bv[4];
                #pragma unroll
                for (int nt = 0; nt < 4; ++nt)
                    bv[nt] = *reinterpret_cast<const short8*>(
                        &Vt[cur][kp][nt * 16 + l15][rsw * 8]);
                __builtin_amdgcn_s_setprio(1);
                #pragma unroll
                for (int nt = 0; nt < 4; ++nt)
                    accB[nt] = __builtin_amdgcn_mfma_f32_16x16x32_bf16(
                        apB, bv[nt], accB[nt], 0, 0, 0);
                lAcc[1] = __builtin_amdgcn_mfma_f32_16x16x32_bf16(
                    apB, ones8, lAcc[1], 0, 0, 0);
                #pragma unroll
                for (int nt = 0; nt < 4; ++nt)
                    accA[nt] = __builtin_amdgcn_mfma_f32_16x16x32_bf16(
                        apA, bv[nt], accA[nt], 0, 0, 0);
                lAcc[0] = __builtin_amdgcn_mfma_f32_16x16x32_bf16(
                    apA, ones8, lAcc[0], 0, 0, 0);
                __builtin_amdgcn_s_setprio(0);
            }
        } else {
            // --- single-tile path (kt > qtA): tile B only
            exp_store(sB, kt == qtB, w);
            #pragma unroll
            for (int kp = 0; kp < 2; ++kp) {
                const short8 apB = *reinterpret_cast<const short8*>(
                    &Ps[w][kp][l15][psw * 8]);
                __builtin_amdgcn_s_setprio(1);
                #pragma unroll
                for (int nt = 0; nt < 4; ++nt) {
                    const short8 bv = *reinterpret_cast<const short8*>(
                        &Vt[cur][kp][nt * 16 + l15][rsw * 8]);
                    accB[nt] = __builtin_amdgcn_mfma_f32_16x16x32_bf16(
                        apB, bv, accB[nt], 0, 0, 0);
                }
                lAcc[1] = __builtin_amdgcn_mfma_f32_16x16x32_bf16(
                    apB, ones8, lAcc[1], 0, 0, 0);
                __builtin_amdgcn_s_setprio(0);
            }
        }
        __syncthreads();
    }

    // Epilogue: lAcc holds the row sums (replicated across l15).
    auto epilogue = [&](floatx4* accO, floatx4& accL, int qt) {
        #pragma unroll
        for (int r = 0; r < 4; ++r) {
            const float inv = 1.f / accL[r];
            const int qrow = qt * 64 + 16 * w + lq * 4 + r;
            #pragma unroll
            for (int nt = 0; nt < 4; ++nt) {
                O[((size_t)(b * SEQ + qrow)) * D_MODEL + h * DK + nt * 16 + l15] =
                    __float2bfloat16(accO[nt][r] * inv);
            }
        }
    };
    epilogue(accA, lAcc[0], qtA);
    epilogue(accB, lAcc[1], qtB);
}

extern "C" void kernel_launch(void* const* d_in, const int* in_sizes, int n_in,
                              void* d_out, int out_size, void* d_ws, size_t ws_size,
                              hipStream_t stream)
{
    const float* x   = (const float*)d_in[0];
    const int*   pos = (const int*)d_in[1];
    const float* Wq  = (const float*)d_in[2];
    const float* Wk  = (const float*)d_in[3];
    const float* Wv  = (const float*)d_in[4];
    const float* Wo  = (const float*)d_in[5];
    float* out = (float*)d_out;

    bf16* xb    = (bf16*)d_ws;
    bf16* w_all = xb + SEG_X;
    bf16* wob   = w_all + 3 * SEG_W;
    bf16* qkb   = wob + SEG_W;                     // 4096 x 2048 (Q|K roped)
    bf16* vtb   = qkb + (size_t)MROWS * QKSTRIDE;  // 32 bh x 64 d x 2048 s
    bf16* ob    = xb;                              // reuse: x dead after GEMM1

    cast_kernel<<<8192, 256, 0, stream>>>(x, Wq, Wk, Wv, Wo, xb, w_all, wob);
    gemm128_kernel<true><<<dim3(32, 24), 256, 0, stream>>>(
        xb, w_all, qkb, vtb, nullptr, pos);
    flash_attn_kernel<<<dim3(16, 32), 256, 0, stream>>>(qkb, vtb, ob);
    gemm128_kernel<false><<<dim3(32, 8), 256, 0, stream>>>(
        ob, wob, nullptr, nullptr, out, nullptr);
}